// Round 13
// baseline (147.465 us; speedup 1.0000x reference)
//
#include <hip/hip_runtime.h>
#include <hip/hip_fp16.h>
#include <cstdint>
#include <cfloat>
#include <cstddef>

#define N_TOK 16384
#define K_CODE 8192
#define D_EMB 256
#define BM 128
#define BN 256
#define BK 64
#define KSPLIT 8
#define KRANGE (K_CODE / KSPLIT)   // 1024
#define NCAND (KSPLIT * 2)         // 16

typedef __attribute__((ext_vector_type(4))) float f32x4;
typedef _Float16 half8 __attribute__((ext_vector_type(8)));

__device__ __forceinline__ unsigned umin_(unsigned a, unsigned b) { return a < b ? a : b; }
__device__ __forceinline__ unsigned umax_(unsigned a, unsigned b) { return a > b ? a : b; }
__device__ __forceinline__ unsigned enc_f32(float v) {
  unsigned u = __float_as_uint(v);
  return (u & 0x80000000u) ? ~u : (u | 0x80000000u);   // order-preserving
}

// ---------------- e2[k] = sum(embeds[k,:]^2)  (exact fp32) ------------------
__global__ __launch_bounds__(256) void e2_kernel(const float* __restrict__ embeds,
                                                 float* __restrict__ e2) {
  const int row  = blockIdx.x * 4 + (threadIdx.x >> 6);
  const int lane = threadIdx.x & 63;
  float4 v = *reinterpret_cast<const float4*>(embeds + (size_t)row * D_EMB + lane * 4);
  float s = v.x * v.x + v.y * v.y + v.z * v.z + v.w * v.w;
#pragma unroll
  for (int m = 32; m > 0; m >>= 1) s += __shfl_xor(s, m, 64);
  if (lane == 0) e2[row] = s;
}

// ---------------- f32 -> f16 row conversion (RNE) ---------------------------
__global__ __launch_bounds__(256) void cvt_f16_kernel(const float* __restrict__ src,
                                                      unsigned short* __restrict__ dst) {
  const int i = blockIdx.x * 256 + threadIdx.x;   // one float4 -> ushort4
  const float4 v = *reinterpret_cast<const float4*>(src + (size_t)i * 4);
  ushort4 h;
  h.x = __half_as_ushort(__float2half(v.x));
  h.y = __half_as_ushort(__float2half(v.y));
  h.z = __half_as_ushort(__float2half(v.z));
  h.w = __half_as_ushort(__float2half(v.w));
  *reinterpret_cast<ushort4*>(dst + (size_t)i * 4) = h;
}

// ------------- screening: fp16 MFMA GEMM + fused top-2 per kpart ------------
// 4 waves, 2x2 grid, wave tile 64x128 (4x8 acc): LDS-read intensity
// M*N/(M+N) = 42.7 FLOP/B (vs 21.8 at 64x32) -- attacks the measured
// ds_read_b128 bandwidth ceiling (~85 B/cyc/CU).
// dist = e2[n] - 2 * sum_d A[m][d]*B[n][d]
// packed key: u32(256*e2 - 512*dot) << 13 | col   (monotone in dist)
__global__ __launch_bounds__(256, 2) void vq_mfma_kernel(
    const unsigned short* __restrict__ Ah,     // [16384][256] f16 bits
    const unsigned short* __restrict__ Bh,     // [8192][256]  f16 bits
    const float* __restrict__ e2,
    unsigned* __restrict__ cand_out) {         // [NCAND][N_TOK] packed keys
  __shared__ unsigned short Asmem[BM * BK];    // 16 KB, rows of 128 B, XOR-swizzled
  __shared__ unsigned short Bsmem[BN * BK];    // 32 KB
  __shared__ unsigned candL[2][BM][2];         // 2 KB: per-(wc) sorted pairs

  const int tid  = threadIdx.x;
  const int lane = tid & 63;
  const int wid  = tid >> 6;
  const int wr   = wid >> 1;     // 0..1 : 64-row half
  const int wc   = wid & 1;      // 0..1 : 128-col half
  const int lrow = lane & 15;
  const int lk   = lane >> 4;

  const int mtile = blockIdx.x & 127;
  const int kpart = blockIdx.x >> 7;           // 0..7
  const int m0    = mtile * BM;
  const int kbeg  = kpart * KRANGE;

  // staging map: LDS byte b = i*4096 + tid*16 (linear dest for global_load_lds);
  // row = b>>7, slot s = (b>>4)&7; fetch global chunk c = s ^ (row&7) so the
  // swizzled read (off ^ ((row&7)<<4)) finds X[row][c] at slot s.
  int srowA[4], scolA[4];
#pragma unroll
  for (int i = 0; i < 4; ++i) {
    const int b = i * 4096 + tid * 16;
    const int r = b >> 7;
    const int s = (b >> 4) & 7;
    srowA[i] = r;
    scolA[i] = (s ^ (r & 7)) * 8;
  }
  int srowB[8], scolB[8];
#pragma unroll
  for (int i = 0; i < 8; ++i) {
    const int b = i * 4096 + tid * 16;
    const int r = b >> 7;
    const int s = (b >> 4) & 7;
    srowB[i] = r;
    scolB[i] = (s ^ (r & 7)) * 8;
  }

  char* Ab = reinterpret_cast<char*>(Asmem);
  char* Bb = reinterpret_cast<char*>(Bsmem);

  unsigned t1[4][4], t2[4][4];   // sorted packed top-2 per (mi,r)
#pragma unroll
  for (int mi = 0; mi < 4; ++mi)
#pragma unroll
    for (int r = 0; r < 4; ++r) { t1[mi][r] = 0xFFFFFFFFu; t2[mi][r] = 0xFFFFFFFFu; }

  for (int k0 = kbeg; k0 < kbeg + KRANGE; k0 += BN) {
    f32x4 acc[4][8];
#pragma unroll
    for (int mi = 0; mi < 4; ++mi)
#pragma unroll
      for (int ni = 0; ni < 8; ++ni) acc[mi][ni] = (f32x4)0.0f;

    for (int d0 = 0; d0 < D_EMB; d0 += BK) {
      __syncthreads();   // previous step's readers done before overwrite
#pragma unroll
      for (int i = 0; i < 4; ++i) {
        const int b = i * 4096 + tid * 16;
        __builtin_amdgcn_global_load_lds(
            (const __attribute__((address_space(1))) void*)(
                Ah + (size_t)(m0 + srowA[i]) * D_EMB + d0 + scolA[i]),
            (__attribute__((address_space(3))) void*)(Ab + b), 16, 0, 0);
      }
#pragma unroll
      for (int i = 0; i < 8; ++i) {
        const int b = i * 4096 + tid * 16;
        __builtin_amdgcn_global_load_lds(
            (const __attribute__((address_space(1))) void*)(
                Bh + (size_t)(k0 + srowB[i]) * D_EMB + d0 + scolB[i]),
            (__attribute__((address_space(3))) void*)(Bb + b), 16, 0, 0);
      }
      __syncthreads();   // vmcnt(0) drain + visibility

#pragma unroll
      for (int kk = 0; kk < 2; ++kk) {
        half8 afr[4], bfr[8];
#pragma unroll
        for (int mi = 0; mi < 4; ++mi) {
          const int row = wr * 64 + mi * 16 + lrow;
          const int off = row * 128 + (((kk * 64) + lk * 16) ^ ((row & 7) << 4));
          afr[mi] = *reinterpret_cast<const half8*>(Ab + off);
        }
#pragma unroll
        for (int ni = 0; ni < 8; ++ni) {
          const int row = wc * 128 + ni * 16 + lrow;
          const int off = row * 128 + (((kk * 64) + lk * 16) ^ ((row & 7) << 4));
          bfr[ni] = *reinterpret_cast<const half8*>(Bb + off);
        }
#pragma unroll
        for (int mi = 0; mi < 4; ++mi)
#pragma unroll
          for (int ni = 0; ni < 8; ++ni)
            acc[mi][ni] = __builtin_amdgcn_mfma_f32_16x16x32_f16(
                afr[mi], bfr[ni], acc[mi][ni], 0, 0, 0);
      }
    }

    // epilogue: C layout col=lane&15, row=(lane>>4)*4+r ; 8-way tournament
    const int colb = k0 + wc * 128;
    int   col8[8];
    float eb8[8];
#pragma unroll
    for (int ni = 0; ni < 8; ++ni) {
      col8[ni] = colb + ni * 16 + lrow;
      eb8[ni]  = e2[col8[ni]] * 256.0f;
    }
#pragma unroll
    for (int mi = 0; mi < 4; ++mi)
#pragma unroll
      for (int r = 0; r < 4; ++r) {
        unsigned p[8];
#pragma unroll
        for (int ni = 0; ni < 8; ++ni) {
          const float q = fmaf(acc[mi][ni][r], -512.0f, eb8[ni]);  // 256*dist
          p[ni] = (((unsigned)q) << 13) | (unsigned)col8[ni];
        }
        const unsigned s0 = umin_(p[0], p[1]), l0 = umax_(p[0], p[1]);
        const unsigned s1 = umin_(p[2], p[3]), l1 = umax_(p[2], p[3]);
        const unsigned s2 = umin_(p[4], p[5]), l2 = umax_(p[4], p[5]);
        const unsigned s3 = umin_(p[6], p[7]), l3 = umax_(p[6], p[7]);
        const unsigned a1 = umin_(s0, s1);
        const unsigned a2 = umin_(umax_(s0, s1), umin_(l0, l1));
        const unsigned b1 = umin_(s2, s3);
        const unsigned b2 = umin_(umax_(s2, s3), umin_(l2, l3));
        const unsigned m1 = umin_(a1, b1);
        const unsigned m2 = umin_(umax_(a1, b1), umin_(a2, b2));
        const unsigned o1 = t1[mi][r];
        t1[mi][r] = umin_(o1, m1);
        t2[mi][r] = umin_(umax_(o1, m1), umin_(t2[mi][r], m2));
      }
  }

  // cross-lane top-2 merge over the 16 column-lanes, then cross-wave (wc)
  __syncthreads();
#pragma unroll
  for (int mi = 0; mi < 4; ++mi)
#pragma unroll
    for (int r = 0; r < 4; ++r) {
      unsigned a1 = t1[mi][r], a2 = t2[mi][r];
#pragma unroll
      for (int m = 1; m <= 8; m <<= 1) {
        const unsigned b1 = (unsigned)__shfl_xor((int)a1, m, 64);
        const unsigned b2 = (unsigned)__shfl_xor((int)a2, m, 64);
        const unsigned n1 = umin_(a1, b1);
        const unsigned n2 = umin_(umax_(a1, b1), umin_(a2, b2));
        a1 = n1; a2 = n2;
      }
      if (lrow == 0) {
        const int row = wr * 64 + mi * 16 + lk * 4 + r;
        candL[wc][row][0] = a1;
        candL[wc][row][1] = a2;
      }
    }
  __syncthreads();
  if (tid < BM) {
    const unsigned a1 = candL[0][tid][0], a2 = candL[0][tid][1];
    const unsigned b1 = candL[1][tid][0], b2 = candL[1][tid][1];
    const unsigned m1 = umin_(a1, b1);
    const unsigned m2 = umin_(umax_(a1, b1), umin_(a2, b2));
    cand_out[(size_t)(kpart * 2 + 0) * N_TOK + m0 + tid] = m1;   // full packed
    cand_out[(size_t)(kpart * 2 + 1) * N_TOK + m0 + tid] = m2;
  }
}

// ------------- refine: top-4 of 16 by fp16 score, exact fp32 rescore --------
__global__ __launch_bounds__(256) void refine16_kernel(
    const float* __restrict__ inputs, const float* __restrict__ embeds,
    const float* __restrict__ e2, const unsigned* __restrict__ cand,
    float* __restrict__ out) {
  const int token = blockIdx.x * 4 + (threadIdx.x >> 6);
  const int lane  = threadIdx.x & 63;

  // lane c<16 holds candidate c's packed key; 4 rounds of wave-min + knockout
  unsigned v = 0xFFFFFFFFu;
  if (lane < NCAND) v = cand[(size_t)lane * N_TOK + token];
  int picks[4];
#pragma unroll
  for (int rnd = 0; rnd < 4; ++rnd) {
    unsigned m = v;
#pragma unroll
    for (int s = 32; s > 0; s >>= 1) m = umin_(m, (unsigned)__shfl_xor((int)m, s, 64));
    picks[rnd] = (int)(m & 0x1FFFu);
    if (v == m) v = 0xFFFFFFFFu;   // knock out winner (packed keys are unique)
  }

  const float4 xv = *reinterpret_cast<const float4*>(inputs + (size_t)token * D_EMB + lane * 4);
  float dots[4];
#pragma unroll
  for (int c = 0; c < 4; ++c) {
    const float4 ev = *reinterpret_cast<const float4*>(embeds + (size_t)picks[c] * D_EMB + lane * 4);
    float d = xv.x * ev.x;
    d = fmaf(xv.y, ev.y, d); d = fmaf(xv.z, ev.z, d); d = fmaf(xv.w, ev.w, d);
    dots[c] = d;
  }
#pragma unroll
  for (int c = 0; c < 4; ++c)
#pragma unroll
    for (int m = 32; m > 0; m >>= 1) dots[c] += __shfl_xor(dots[c], m, 64);

  unsigned long long best = ~0ull;
#pragma unroll
  for (int c = 0; c < 4; ++c) {
    const float dist = fmaf(-2.0f, dots[c], e2[picks[c]]);
    const unsigned long long p =
        ((unsigned long long)enc_f32(dist) << 32) | (unsigned)picks[c];
    if (p < best) best = p;
  }
  const int widx = (int)(best & 0xFFFFFFFFull);
  const float4 ov = *reinterpret_cast<const float4*>(embeds + (size_t)widx * D_EMB + lane * 4);
  *reinterpret_cast<float4*>(out + (size_t)token * D_EMB + lane * 4) = ov;
}

// ------------- fallback fp32 scorer (round-2, known-good) -------------------
__global__ __launch_bounds__(256, 2) void vq_score_kernel(
    const float* __restrict__ inputs, const float* __restrict__ embeds,
    const float* __restrict__ e2, unsigned long long* __restrict__ keys) {
  __shared__ float A_lds[32 * 132];
  __shared__ float B_lds[32 * 132];
  const int tid = threadIdx.x;
  const int tx = tid & 15, ty = tid >> 4;
  const int mtile = blockIdx.x & 127, kpart = blockIdx.x >> 7;
  const int m0 = mtile * BM, kbeg = kpart * KRANGE;
  float best[8]; int bidx[8];
#pragma unroll
  for (int i = 0; i < 8; ++i) { best[i] = FLT_MAX; bidx[i] = 0x7FFFFFFF; }
  for (int k0 = kbeg; k0 < kbeg + KRANGE; k0 += 128) {
    float acc[8][8];
#pragma unroll
    for (int i = 0; i < 8; ++i)
#pragma unroll
      for (int j = 0; j < 8; ++j) acc[i][j] = 0.0f;
    for (int d0 = 0; d0 < D_EMB; d0 += 32) {
      __syncthreads();
#pragma unroll
      for (int it = 0; it < 4; ++it) {
        const int u = tid + it * 256, m = u >> 3, dg = u & 7;
        float4 va = *reinterpret_cast<const float4*>(inputs + (size_t)(m0 + m) * D_EMB + d0 + dg * 4);
        float4 vb = *reinterpret_cast<const float4*>(embeds + (size_t)(k0 + m) * D_EMB + d0 + dg * 4);
        A_lds[(dg * 4 + 0) * 132 + m] = va.x; A_lds[(dg * 4 + 1) * 132 + m] = va.y;
        A_lds[(dg * 4 + 2) * 132 + m] = va.z; A_lds[(dg * 4 + 3) * 132 + m] = va.w;
        B_lds[(dg * 4 + 0) * 132 + m] = vb.x; B_lds[(dg * 4 + 1) * 132 + m] = vb.y;
        B_lds[(dg * 4 + 2) * 132 + m] = vb.z; B_lds[(dg * 4 + 3) * 132 + m] = vb.w;
      }
      __syncthreads();
#pragma unroll 8
      for (int dd = 0; dd < 32; ++dd) {
        float a[8], b[8];
        *reinterpret_cast<float4*>(&a[0]) = *reinterpret_cast<const float4*>(&A_lds[dd * 132 + ty * 8]);
        *reinterpret_cast<float4*>(&a[4]) = *reinterpret_cast<const float4*>(&A_lds[dd * 132 + ty * 8 + 4]);
        *reinterpret_cast<float4*>(&b[0]) = *reinterpret_cast<const float4*>(&B_lds[dd * 132 + tx * 8]);
        *reinterpret_cast<float4*>(&b[4]) = *reinterpret_cast<const float4*>(&B_lds[dd * 132 + tx * 8 + 4]);
#pragma unroll
        for (int i = 0; i < 8; ++i)
#pragma unroll
          for (int j = 0; j < 8; ++j) acc[i][j] = fmaf(a[i], b[j], acc[i][j]);
      }
    }
#pragma unroll
    for (int j = 0; j < 8; ++j) {
      const int col = k0 + tx * 8 + j;
      const float ev = e2[col];
#pragma unroll
      for (int i = 0; i < 8; ++i) {
        const float dist = fmaf(-2.0f, acc[i][j], ev);
        if (dist < best[i]) { best[i] = dist; bidx[i] = col; }
      }
    }
  }
  __syncthreads();
  float* bestv = A_lds;
  int* besti = reinterpret_cast<int*>(B_lds);
#pragma unroll
  for (int i = 0; i < 8; ++i) {
    bestv[(ty * 8 + i) * 16 + tx] = best[i];
    besti[(ty * 8 + i) * 16 + tx] = bidx[i];
  }
  __syncthreads();
  if (tid < BM) {
    float bv = FLT_MAX; int bi = 0x7FFFFFFF;
#pragma unroll
    for (int t = 0; t < 16; ++t) {
      const float v = bestv[tid * 16 + t];
      const int ii = besti[tid * 16 + t];
      if (v < bv || (v == bv && ii < bi)) { bv = v; bi = ii; }
    }
    keys[(size_t)kpart * N_TOK + m0 + tid] =
        ((unsigned long long)enc_f32(bv) << 32) | (unsigned)bi;
  }
}

__global__ __launch_bounds__(256) void gather_kernel(
    const float* __restrict__ embeds, const unsigned long long* __restrict__ keys,
    float* __restrict__ out) {
  const int r    = blockIdx.x * 4 + (threadIdx.x >> 6);
  const int lane = threadIdx.x & 63;
  unsigned long long k = keys[r];
#pragma unroll
  for (int p = 1; p < KSPLIT; ++p) {
    const unsigned long long kp = keys[(size_t)p * N_TOK + r];
    if (kp < k) k = kp;
  }
  const int idx = (int)(k & 0xFFFFFFFFull);
  float4 v = *reinterpret_cast<const float4*>(embeds + (size_t)idx * D_EMB + lane * 4);
  *reinterpret_cast<float4*>(out + (size_t)r * D_EMB + lane * 4) = v;
}

extern "C" void kernel_launch(void* const* d_in, const int* in_sizes, int n_in,
                              void* d_out, int out_size, void* d_ws, size_t ws_size,
                              hipStream_t stream) {
  const float* inputs = (const float*)d_in[0];   // [16384,256] f32
  const float* embeds = (const float*)d_in[1];   // [8192,256] f32
  float* out = (float*)d_out;

  char* ws = (char*)d_ws;
  float* e2 = (float*)ws;                                        // 32 KB @ 0
  unsigned* cand = (unsigned*)(ws + (1 << 20));                  // 1 MB @ 1 MB
  unsigned long long* keys = (unsigned long long*)(ws + (1 << 20));  // fallback alias
  unsigned short* Ahalf = (unsigned short*)(ws + (2 << 20));     // 8 MB @ 2 MB
  unsigned short* Bhalf = (unsigned short*)(ws + (10 << 20));    // 4 MB @ 10 MB
  const size_t need = (size_t)(14 << 20);

  e2_kernel<<<K_CODE / 4, 256, 0, stream>>>(embeds, e2);
  if (ws_size >= need) {
    cvt_f16_kernel<<<(N_TOK * D_EMB / 4) / 256, 256, 0, stream>>>(inputs, Ahalf);
    cvt_f16_kernel<<<(K_CODE * D_EMB / 4) / 256, 256, 0, stream>>>(embeds, Bhalf);
    vq_mfma_kernel<<<(N_TOK / BM) * KSPLIT, 256, 0, stream>>>(Ahalf, Bhalf, e2, cand);
    refine16_kernel<<<N_TOK / 4, 256, 0, stream>>>(inputs, embeds, e2, cand, out);
  } else {
    vq_score_kernel<<<(N_TOK / BM) * KSPLIT, 256, 0, stream>>>(inputs, embeds, e2, keys);
    gather_kernel<<<N_TOK / 4, 256, 0, stream>>>(embeds, keys, out);
  }
}

// Round 16
// 114.134 us; speedup vs baseline: 1.2920x; 1.2920x over previous
//
#include <hip/hip_runtime.h>
#include <hip/hip_fp16.h>
#include <cstdint>
#include <cfloat>
#include <cstddef>

#define N_TOK 16384
#define K_CODE 8192
#define D_EMB 256
#define BM 128
#define BN 128
#define BK 128
#define KSPLIT 8
#define KRANGE (K_CODE / KSPLIT)   // 1024
#define NCAND (KSPLIT * 2)         // 16

typedef __attribute__((ext_vector_type(4))) float f32x4;
typedef _Float16 half8 __attribute__((ext_vector_type(8)));

__device__ __forceinline__ unsigned umin_(unsigned a, unsigned b) { return a < b ? a : b; }
__device__ __forceinline__ unsigned umax_(unsigned a, unsigned b) { return a > b ? a : b; }
__device__ __forceinline__ unsigned enc_f32(float v) {
  unsigned u = __float_as_uint(v);
  return (u & 0x80000000u) ? ~u : (u | 0x80000000u);   // order-preserving
}

// ---------------- e2[k] = sum(embeds[k,:]^2)  (exact fp32) ------------------
__global__ __launch_bounds__(256) void e2_kernel(const float* __restrict__ embeds,
                                                 float* __restrict__ e2) {
  const int row  = blockIdx.x * 4 + (threadIdx.x >> 6);
  const int lane = threadIdx.x & 63;
  float4 v = *reinterpret_cast<const float4*>(embeds + (size_t)row * D_EMB + lane * 4);
  float s = v.x * v.x + v.y * v.y + v.z * v.z + v.w * v.w;
#pragma unroll
  for (int m = 32; m > 0; m >>= 1) s += __shfl_xor(s, m, 64);
  if (lane == 0) e2[row] = s;
}

// ---------------- f32 -> f16 row conversion (RNE) ---------------------------
__global__ __launch_bounds__(256) void cvt_f16_kernel(const float* __restrict__ src,
                                                      unsigned short* __restrict__ dst) {
  const int i = blockIdx.x * 256 + threadIdx.x;   // one float4 -> ushort4
  const float4 v = *reinterpret_cast<const float4*>(src + (size_t)i * 4);
  ushort4 h;
  h.x = __half_as_ushort(__float2half(v.x));
  h.y = __half_as_ushort(__float2half(v.y));
  h.z = __half_as_ushort(__float2half(v.z));
  h.w = __half_as_ushort(__float2half(v.w));
  *reinterpret_cast<ushort4*>(dst + (size_t)i * 4) = h;
}

// ------------- screening: fp16 MFMA GEMM + fused top-2 per kpart ------------
// Round-9 structure with BK=128: 16 iterations (vs 32), 64 MFMA + 32 ds_read
// between barriers -- halves the vmcnt(0)-drain count. 64x64 wave tiles
// (proven register shape), single-buffered 66 KB LDS, 2 blocks/CU.
// dist = e2[n] - 2 * sum_d A[m][d]*B[n][d]
// packed key: u32(256*e2 - 512*dot) << 13 | col   (monotone in dist)
__global__ __launch_bounds__(256, 2) void vq_mfma_kernel(
    const unsigned short* __restrict__ Ah,     // [16384][256] f16 bits
    const unsigned short* __restrict__ Bh,     // [8192][256]  f16 bits
    const float* __restrict__ e2,
    unsigned* __restrict__ cand_out) {         // [NCAND][N_TOK] packed keys
  __shared__ unsigned short Asmem[BM * BK];    // 32 KB, rows of 256 B, XOR-swizzled
  __shared__ unsigned short Bsmem[BN * BK];    // 32 KB
  __shared__ unsigned candL[2][BM][2];         // 2 KB

  const int tid  = threadIdx.x;
  const int lane = tid & 63;
  const int wid  = tid >> 6;
  const int wr   = wid >> 1;     // 2x2 wave grid, 64x64 out each
  const int wc   = wid & 1;
  const int lrow = lane & 15;
  const int lk   = lane >> 4;

  const int mtile = blockIdx.x & 127;
  const int kpart = blockIdx.x >> 7;           // 0..7
  const int m0    = mtile * BM;
  const int kbeg  = kpart * KRANGE;

  // staging map (256B rows): LDS byte b = i*4096 + tid*16 (linear dest);
  // row = b>>8, slot s = (b>>4)&15; fetch global chunk c = s ^ (row&7) so the
  // swizzled read (off ^ ((row&7)<<4)) finds X[row][c] at slot s.
  int srow[8], scol[8];
#pragma unroll
  for (int i = 0; i < 8; ++i) {
    const int b = i * 4096 + tid * 16;
    const int r = b >> 8;
    const int s = (b >> 4) & 15;
    srow[i] = r;
    scol[i] = (s ^ (r & 7)) * 8;
  }

  char* Ab = reinterpret_cast<char*>(Asmem);
  char* Bb = reinterpret_cast<char*>(Bsmem);

  unsigned t1[4][4], t2[4][4];   // sorted packed top-2 per (mi,r)
#pragma unroll
  for (int mi = 0; mi < 4; ++mi)
#pragma unroll
    for (int r = 0; r < 4; ++r) { t1[mi][r] = 0xFFFFFFFFu; t2[mi][r] = 0xFFFFFFFFu; }

  for (int k0 = kbeg; k0 < kbeg + KRANGE; k0 += BN) {
    f32x4 acc[4][4];
#pragma unroll
    for (int mi = 0; mi < 4; ++mi)
#pragma unroll
      for (int ni = 0; ni < 4; ++ni) acc[mi][ni] = (f32x4)0.0f;

    for (int d0 = 0; d0 < D_EMB; d0 += BK) {
      __syncthreads();   // previous step's readers done before overwrite
#pragma unroll
      for (int i = 0; i < 8; ++i) {
        const int b = i * 4096 + tid * 16;
        __builtin_amdgcn_global_load_lds(
            (const __attribute__((address_space(1))) void*)(
                Ah + (size_t)(m0 + srow[i]) * D_EMB + d0 + scol[i]),
            (__attribute__((address_space(3))) void*)(Ab + b), 16, 0, 0);
      }
#pragma unroll
      for (int i = 0; i < 8; ++i) {
        const int b = i * 4096 + tid * 16;
        __builtin_amdgcn_global_load_lds(
            (const __attribute__((address_space(1))) void*)(
                Bh + (size_t)(k0 + srow[i]) * D_EMB + d0 + scol[i]),
            (__attribute__((address_space(3))) void*)(Bb + b), 16, 0, 0);
      }
      __syncthreads();   // vmcnt(0) drain + visibility

#pragma unroll
      for (int kk = 0; kk < 4; ++kk) {       // BK=128 -> 4 K-slices of 32
        half8 afr[4], bfr[4];
#pragma unroll
        for (int mi = 0; mi < 4; ++mi) {
          const int row = wr * 64 + mi * 16 + lrow;
          const int off = row * 256 + (((kk * 64) + lk * 16) ^ ((row & 7) << 4));
          afr[mi] = *reinterpret_cast<const half8*>(Ab + off);
        }
#pragma unroll
        for (int ni = 0; ni < 4; ++ni) {
          const int row = wc * 64 + ni * 16 + lrow;
          const int off = row * 256 + (((kk * 64) + lk * 16) ^ ((row & 7) << 4));
          bfr[ni] = *reinterpret_cast<const half8*>(Bb + off);
        }
#pragma unroll
        for (int mi = 0; mi < 4; ++mi)
#pragma unroll
          for (int ni = 0; ni < 4; ++ni)
            acc[mi][ni] = __builtin_amdgcn_mfma_f32_16x16x32_f16(
                afr[mi], bfr[ni], acc[mi][ni], 0, 0, 0);
      }
    }

    // epilogue: C layout col=lane&15, row=(lane>>4)*4+r ; 4-way tournament
    const int colb = k0 + wc * 64;
    int   col4[4];
    float eb4[4];
#pragma unroll
    for (int ni = 0; ni < 4; ++ni) {
      col4[ni] = colb + ni * 16 + lrow;
      eb4[ni]  = e2[col4[ni]] * 256.0f;
    }
#pragma unroll
    for (int mi = 0; mi < 4; ++mi)
#pragma unroll
      for (int r = 0; r < 4; ++r) {
        unsigned p[4];
#pragma unroll
        for (int ni = 0; ni < 4; ++ni) {
          const float q = fmaf(acc[mi][ni][r], -512.0f, eb4[ni]);  // 256*dist
          p[ni] = (((unsigned)q) << 13) | (unsigned)col4[ni];
        }
        const unsigned s1 = umin_(p[0], p[1]), l1 = umax_(p[0], p[1]);
        const unsigned s2 = umin_(p[2], p[3]), l2 = umax_(p[2], p[3]);
        const unsigned m1 = umin_(s1, s2);
        const unsigned m2 = umin_(umax_(s1, s2), umin_(l1, l2));
        const unsigned o1 = t1[mi][r];
        t1[mi][r] = umin_(o1, m1);
        t2[mi][r] = umin_(umax_(o1, m1), umin_(t2[mi][r], m2));
      }
  }

  // cross-lane top-2 merge over the 16 column-lanes, then cross-wave (wc)
  __syncthreads();
#pragma unroll
  for (int mi = 0; mi < 4; ++mi)
#pragma unroll
    for (int r = 0; r < 4; ++r) {
      unsigned a1 = t1[mi][r], a2 = t2[mi][r];
#pragma unroll
      for (int m = 1; m <= 8; m <<= 1) {
        const unsigned b1 = (unsigned)__shfl_xor((int)a1, m, 64);
        const unsigned b2 = (unsigned)__shfl_xor((int)a2, m, 64);
        const unsigned n1 = umin_(a1, b1);
        const unsigned n2 = umin_(umax_(a1, b1), umin_(a2, b2));
        a1 = n1; a2 = n2;
      }
      if (lrow == 0) {
        const int row = wr * 64 + mi * 16 + lk * 4 + r;
        candL[wc][row][0] = a1;
        candL[wc][row][1] = a2;
      }
    }
  __syncthreads();
  if (tid < BM) {
    const unsigned a1 = candL[0][tid][0], a2 = candL[0][tid][1];
    const unsigned b1 = candL[1][tid][0], b2 = candL[1][tid][1];
    const unsigned m1 = umin_(a1, b1);
    const unsigned m2 = umin_(umax_(a1, b1), umin_(a2, b2));
    cand_out[(size_t)(kpart * 2 + 0) * N_TOK + m0 + tid] = m1;   // full packed
    cand_out[(size_t)(kpart * 2 + 1) * N_TOK + m0 + tid] = m2;
  }
}

// ------------- refine: top-4 of 16 by fp16 score, exact fp32 rescore --------
__global__ __launch_bounds__(256) void refine16_kernel(
    const float* __restrict__ inputs, const float* __restrict__ embeds,
    const float* __restrict__ e2, const unsigned* __restrict__ cand,
    float* __restrict__ out) {
  const int token = blockIdx.x * 4 + (threadIdx.x >> 6);
  const int lane  = threadIdx.x & 63;

  // lane c<16 holds candidate c's packed key; 4 rounds of wave-min + knockout
  unsigned v = 0xFFFFFFFFu;
  if (lane < NCAND) v = cand[(size_t)lane * N_TOK + token];
  int picks[4];
#pragma unroll
  for (int rnd = 0; rnd < 4; ++rnd) {
    unsigned m = v;
#pragma unroll
    for (int s = 32; s > 0; s >>= 1) m = umin_(m, (unsigned)__shfl_xor((int)m, s, 64));
    picks[rnd] = (int)(m & 0x1FFFu);
    if (v == m) v = 0xFFFFFFFFu;   // knock out winner (packed keys are unique)
  }

  const float4 xv = *reinterpret_cast<const float4*>(inputs + (size_t)token * D_EMB + lane * 4);
  float dots[4];
#pragma unroll
  for (int c = 0; c < 4; ++c) {
    const float4 ev = *reinterpret_cast<const float4*>(embeds + (size_t)picks[c] * D_EMB + lane * 4);
    float d = xv.x * ev.x;
    d = fmaf(xv.y, ev.y, d); d = fmaf(xv.z, ev.z, d); d = fmaf(xv.w, ev.w, d);
    dots[c] = d;
  }
#pragma unroll
  for (int c = 0; c < 4; ++c)
#pragma unroll
    for (int m = 32; m > 0; m >>= 1) dots[c] += __shfl_xor(dots[c], m, 64);

  unsigned long long best = ~0ull;
#pragma unroll
  for (int c = 0; c < 4; ++c) {
    const float dist = fmaf(-2.0f, dots[c], e2[picks[c]]);
    const unsigned long long p =
        ((unsigned long long)enc_f32(dist) << 32) | (unsigned)picks[c];
    if (p < best) best = p;
  }
  const int widx = (int)(best & 0xFFFFFFFFull);
  const float4 ov = *reinterpret_cast<const float4*>(embeds + (size_t)widx * D_EMB + lane * 4);
  *reinterpret_cast<float4*>(out + (size_t)token * D_EMB + lane * 4) = ov;
}

// ------------- fallback fp32 scorer (round-2, known-good) -------------------
__global__ __launch_bounds__(256, 2) void vq_score_kernel(
    const float* __restrict__ inputs, const float* __restrict__ embeds,
    const float* __restrict__ e2, unsigned long long* __restrict__ keys) {
  __shared__ float A_lds[32 * 132];
  __shared__ float B_lds[32 * 132];
  const int tid = threadIdx.x;
  const int tx = tid & 15, ty = tid >> 4;
  const int mtile = blockIdx.x & 127, kpart = blockIdx.x >> 7;
  const int m0 = mtile * BM, kbeg = kpart * KRANGE;
  float best[8]; int bidx[8];
#pragma unroll
  for (int i = 0; i < 8; ++i) { best[i] = FLT_MAX; bidx[i] = 0x7FFFFFFF; }
  for (int k0 = kbeg; k0 < kbeg + KRANGE; k0 += 128) {
    float acc[8][8];
#pragma unroll
    for (int i = 0; i < 8; ++i)
#pragma unroll
      for (int j = 0; j < 8; ++j) acc[i][j] = 0.0f;
    for (int d0 = 0; d0 < D_EMB; d0 += 32) {
      __syncthreads();
#pragma unroll
      for (int it = 0; it < 4; ++it) {
        const int u = tid + it * 256, m = u >> 3, dg = u & 7;
        float4 va = *reinterpret_cast<const float4*>(inputs + (size_t)(m0 + m) * D_EMB + d0 + dg * 4);
        float4 vb = *reinterpret_cast<const float4*>(embeds + (size_t)(k0 + m) * D_EMB + d0 + dg * 4);
        A_lds[(dg * 4 + 0) * 132 + m] = va.x; A_lds[(dg * 4 + 1) * 132 + m] = va.y;
        A_lds[(dg * 4 + 2) * 132 + m] = va.z; A_lds[(dg * 4 + 3) * 132 + m] = va.w;
        B_lds[(dg * 4 + 0) * 132 + m] = vb.x; B_lds[(dg * 4 + 1) * 132 + m] = vb.y;
        B_lds[(dg * 4 + 2) * 132 + m] = vb.z; B_lds[(dg * 4 + 3) * 132 + m] = vb.w;
      }
      __syncthreads();
#pragma unroll 8
      for (int dd = 0; dd < 32; ++dd) {
        float a[8], b[8];
        *reinterpret_cast<float4*>(&a[0]) = *reinterpret_cast<const float4*>(&A_lds[dd * 132 + ty * 8]);
        *reinterpret_cast<float4*>(&a[4]) = *reinterpret_cast<const float4*>(&A_lds[dd * 132 + ty * 8 + 4]);
        *reinterpret_cast<float4*>(&b[0]) = *reinterpret_cast<const float4*>(&B_lds[dd * 132 + tx * 8]);
        *reinterpret_cast<float4*>(&b[4]) = *reinterpret_cast<const float4*>(&B_lds[dd * 132 + tx * 8 + 4]);
#pragma unroll
        for (int i = 0; i < 8; ++i)
#pragma unroll
          for (int j = 0; j < 8; ++j) acc[i][j] = fmaf(a[i], b[j], acc[i][j]);
      }
    }
#pragma unroll
    for (int j = 0; j < 8; ++j) {
      const int col = k0 + tx * 8 + j;
      const float ev = e2[col];
#pragma unroll
      for (int i = 0; i < 8; ++i) {
        const float dist = fmaf(-2.0f, acc[i][j], ev);
        if (dist < best[i]) { best[i] = dist; bidx[i] = col; }
      }
    }
  }
  __syncthreads();
  float* bestv = A_lds;
  int* besti = reinterpret_cast<int*>(B_lds);
#pragma unroll
  for (int i = 0; i < 8; ++i) {
    bestv[(ty * 8 + i) * 16 + tx] = best[i];
    besti[(ty * 8 + i) * 16 + tx] = bidx[i];
  }
  __syncthreads();
  if (tid < BM) {
    float bv = FLT_MAX; int bi = 0x7FFFFFFF;
#pragma unroll
    for (int t = 0; t < 16; ++t) {
      const float v = bestv[tid * 16 + t];
      const int ii = besti[tid * 16 + t];
      if (v < bv || (v == bv && ii < bi)) { bv = v; bi = ii; }
    }
    keys[(size_t)kpart * N_TOK + m0 + tid] =
        ((unsigned long long)enc_f32(bv) << 32) | (unsigned)bi;
  }
}

__global__ __launch_bounds__(256) void gather_kernel(
    const float* __restrict__ embeds, const unsigned long long* __restrict__ keys,
    float* __restrict__ out) {
  const int r    = blockIdx.x * 4 + (threadIdx.x >> 6);
  const int lane = threadIdx.x & 63;
  unsigned long long k = keys[r];
#pragma unroll
  for (int p = 1; p < KSPLIT; ++p) {
    const unsigned long long kp = keys[(size_t)p * N_TOK + r];
    if (kp < k) k = kp;
  }
  const int idx = (int)(k & 0xFFFFFFFFull);
  float4 v = *reinterpret_cast<const float4*>(embeds + (size_t)idx * D_EMB + lane * 4);
  *reinterpret_cast<float4*>(out + (size_t)r * D_EMB + lane * 4) = v;
}

extern "C" void kernel_launch(void* const* d_in, const int* in_sizes, int n_in,
                              void* d_out, int out_size, void* d_ws, size_t ws_size,
                              hipStream_t stream) {
  const float* inputs = (const float*)d_in[0];   // [16384,256] f32
  const float* embeds = (const float*)d_in[1];   // [8192,256] f32
  float* out = (float*)d_out;

  char* ws = (char*)d_ws;
  float* e2 = (float*)ws;                                        // 32 KB @ 0
  unsigned* cand = (unsigned*)(ws + (1 << 20));                  // 1 MB @ 1 MB
  unsigned long long* keys = (unsigned long long*)(ws + (1 << 20));  // fallback alias
  unsigned short* Ahalf = (unsigned short*)(ws + (2 << 20));     // 8 MB @ 2 MB
  unsigned short* Bhalf = (unsigned short*)(ws + (10 << 20));    // 4 MB @ 10 MB
  const size_t need = (size_t)(14 << 20);

  e2_kernel<<<K_CODE / 4, 256, 0, stream>>>(embeds, e2);
  if (ws_size >= need) {
    cvt_f16_kernel<<<(N_TOK * D_EMB / 4) / 256, 256, 0, stream>>>(inputs, Ahalf);
    cvt_f16_kernel<<<(K_CODE * D_EMB / 4) / 256, 256, 0, stream>>>(embeds, Bhalf);
    vq_mfma_kernel<<<(N_TOK / BM) * KSPLIT, 256, 0, stream>>>(Ahalf, Bhalf, e2, cand);
    refine16_kernel<<<N_TOK / 4, 256, 0, stream>>>(inputs, embeds, e2, cand, out);
  } else {
    vq_score_kernel<<<(N_TOK / BM) * KSPLIT, 256, 0, stream>>>(inputs, embeds, e2, keys);
    gather_kernel<<<N_TOK / 4, 256, 0, stream>>>(embeds, keys, out);
  }
}